// Round 3
// baseline (704.230 us; speedup 1.0000x reference)
//
#include <hip/hip_runtime.h>
#include <math.h>

#define Bq 4
#define Cc 256
#define Tt 2048
#define Kk 7
#define NTOP 10
#define CG 8
#define Ll 2
#define NO 768   // fused pointwise outputs: 256 h | 256 ctr | 256 nbr

typedef __attribute__((ext_vector_type(8))) short short8;
typedef __attribute__((ext_vector_type(4))) float floatx4;
typedef __attribute__((ext_vector_type(2))) float floatx2;

__device__ __forceinline__ float gelu_f(float v) {
  return 0.5f * v * (1.0f + erff(v * 0.70710678118654752440f));
}

// A&S 7.1.26 rational erf (~1e-6 eff err in fp32). SAFE ONLY on paths that do
// not feed a later top-k: R10 proved a ~1e-6 x1 perturbation flips layer-2 KNN.
__device__ __forceinline__ float erf_fast(float x) {
  float ax = fabsf(x);
  float t = __builtin_amdgcn_rcpf(fmaf(0.3275911f, ax, 1.0f));
  float y = t * (0.254829592f + t * (-0.284496736f + t * (1.421413741f +
            t * (-1.453152027f + t * 1.061405429f))));
  float r = 1.0f - y * __expf(-ax * ax);
  return copysignf(r, x);
}
__device__ __forceinline__ float gelu_fast(float v) {
  return 0.5f * v * (1.0f + erf_fast(v * 0.70710678118654752440f));
}

// xT[b][t][c] = x[b][c][t]; also emits bf16 hi/lo split
__global__ void transpose_x(const float* __restrict__ x, float* __restrict__ xT,
                            unsigned short* __restrict__ xh,
                            unsigned short* __restrict__ xl) {
  __shared__ float tile[32][33];
  int b = blockIdx.z;
  int t0 = blockIdx.x * 32, c0 = blockIdx.y * 32;
  int tx = threadIdx.x, ty = threadIdx.y;
  const float* xb = x + (size_t)b * Cc * Tt;
  for (int r = ty; r < 32; r += 8)
    tile[r][tx] = xb[(size_t)(c0 + r) * Tt + t0 + tx];
  __syncthreads();
  size_t base = (size_t)b * Tt * Cc;
  for (int r = ty; r < 32; r += 8) {
    float v = tile[tx][r];
    size_t o = base + (size_t)(t0 + r) * Cc + c0 + tx;
    xT[o] = v;
    unsigned int u = __float_as_uint(v);
    unsigned short h = (unsigned short)((u + 0x7fffu + ((u >> 16) & 1u)) >> 16);
    float f = v - __uint_as_float((unsigned int)h << 16);
    unsigned int ul = __float_as_uint(f);
    xh[o] = h;
    xl[o] = (unsigned short)((ul + 0x7fffu + ((ul >> 16) & 1u)) >> 16);
  }
}

// plain fp32 transpose: dst[b][t][c] = src[b][c][t]  (for nbr -> nbrT)
__global__ void transpose_f(const float* __restrict__ src, float* __restrict__ dst) {
  __shared__ float tile[32][33];
  int b = blockIdx.z;
  int t0 = blockIdx.x * 32, c0 = blockIdx.y * 32;
  int tx = threadIdx.x, ty = threadIdx.y;
  const float* sb = src + (size_t)b * Cc * Tt;
  for (int r = ty; r < 32; r += 8)
    tile[r][tx] = sb[(size_t)(c0 + r) * Tt + t0 + tx];
  __syncthreads();
  float* db = dst + (size_t)b * Tt * Cc;
  for (int r = ty; r < 32; r += 8)
    db[(size_t)(t0 + r) * Cc + c0 + tx] = tile[tx][r];
}

// squared norms from xT; wave per row t, 8 rows per block
__global__ __launch_bounds__(512) void sqnorm_xt(
    const float* __restrict__ xT, float* __restrict__ xx) {
  int b = blockIdx.y;
  int t = blockIdx.x * 8 + (threadIdx.x >> 6);
  int lane = threadIdx.x & 63;
  const float* row = xT + ((size_t)b * Tt + t) * Cc;
  float4 v = *(const float4*)(row + lane * 4);
  float acc = v.x * v.x + v.y * v.y + v.z * v.z + v.w * v.w;
#pragma unroll
  for (int off = 1; off < 64; off <<= 1) acc += __shfl_xor(acc, off);
  if (lane == 0) xx[(size_t)b * Tt + t] = acc;
}

// fp32 pointwise convs, all 3 ranges in one launch (layer-1 exact path).
// Thread = 8 outputs x 4 tokens, float4 x-loads (32 FMA per load vs 8 before).
// Per-(o,t) fmaf chain remains bias -> ascending c  ==> bit-identical to R12.
__global__ __launch_bounds__(256) void pw_conv8_all(
    const float* __restrict__ x, const float* __restrict__ tw1,
    const float* __restrict__ tb1, const float* __restrict__ dw1,
    const float* __restrict__ db1, float* __restrict__ hb,
    float* __restrict__ cb, float* __restrict__ nb) {
  int tid = threadIdx.x;
  int wv = tid >> 6, lane = tid & 63;
  int t = blockIdx.x * 1024 + wv * 256 + lane * 4;   // 4 consecutive tokens
  int oy = blockIdx.y;
  int b = blockIdx.z;
  int range = oy >> 5;            // 0: h  1: ctr  2: nbr
  int o0 = (oy & 31) * 8;
  const float* W; int wstride, woff; const float* bias; float* dst; int dg;
  if (range == 0)      { W = tw1; wstride = Cc;     woff = 0;  bias = tb1;     dst = hb; dg = 1; }
  else if (range == 1) { W = dw1; wstride = 2 * Cc; woff = Cc; bias = db1;     dst = cb; dg = 0; }
  else                 { W = dw1; wstride = 2 * Cc; woff = 0;  bias = nullptr; dst = nb; dg = 0; }
  const float* xp = x + (size_t)b * Cc * Tt + t;
  const float* wp = W + (size_t)o0 * wstride + woff;
  float acc[8][4];
#pragma unroll
  for (int j = 0; j < 8; ++j) {
    float bv = bias ? bias[o0 + j] : 0.f;
#pragma unroll
    for (int e = 0; e < 4; ++e) acc[j][e] = bv;
  }
  for (int c = 0; c < Cc; c += 4) {
    float4 xv0 = *(const float4*)(xp + (size_t)c * Tt);
    float4 xv1 = *(const float4*)(xp + (size_t)(c + 1) * Tt);
    float4 xv2 = *(const float4*)(xp + (size_t)(c + 2) * Tt);
    float4 xv3 = *(const float4*)(xp + (size_t)(c + 3) * Tt);
    float x0[4] = {xv0.x, xv0.y, xv0.z, xv0.w};
    float x1[4] = {xv1.x, xv1.y, xv1.z, xv1.w};
    float x2[4] = {xv2.x, xv2.y, xv2.z, xv2.w};
    float x3[4] = {xv3.x, xv3.y, xv3.z, xv3.w};
#pragma unroll
    for (int j = 0; j < 8; ++j) {
      const float* wr = wp + (size_t)j * wstride + c;   // wave-uniform -> s_load
      float w0 = wr[0], w1 = wr[1], w2 = wr[2], w3 = wr[3];
#pragma unroll
      for (int e = 0; e < 4; ++e) {
        float a = acc[j][e];
        a = fmaf(w0, x0[e], a);
        a = fmaf(w1, x1[e], a);
        a = fmaf(w2, x2[e], a);
        a = fmaf(w3, x3[e], a);
        acc[j][e] = a;
      }
    }
  }
#pragma unroll
  for (int j = 0; j < 8; ++j) {
    float4 r;
    float* rp = (float*)&r;
#pragma unroll
    for (int e = 0; e < 4; ++e) {
      float v = acc[j][e];
      if (dg) v = gelu_f(v);
      rp[e] = v;
    }
    *(float4*)&dst[((size_t)b * Cc + o0 + j) * Tt + t] = r;
  }
}

// concat weights [768][256] -> bf16 hi/lo (layer-2 only)
__global__ __launch_bounds__(256) void wsplit(
    const float* __restrict__ tw1, const float* __restrict__ dw1,
    unsigned short* __restrict__ wh, unsigned short* __restrict__ wl) {
  int o = blockIdx.x;
  int c = threadIdx.x;
  float v;
  if (o < 256) v = tw1[(size_t)o * Cc + c];
  else if (o < 512) v = dw1[(size_t)(o - 256) * (2 * Cc) + Cc + c];
  else v = dw1[(size_t)(o - 512) * (2 * Cc) + c];
  unsigned int u = __float_as_uint(v);
  unsigned short h = (unsigned short)((u + 0x7fffu + ((u >> 16) & 1u)) >> 16);
  float f = v - __uint_as_float((unsigned int)h << 16);
  unsigned int ul = __float_as_uint(f);
  wh[(size_t)o * Cc + c] = h;
  wl[(size_t)o * Cc + c] = (unsigned short)((ul + 0x7fffu + ((ul >> 16) & 1u)) >> 16);
}

// fused pointwise GEMM (layer-2 only)
__global__ __launch_bounds__(256) void pw_gemm(
    const unsigned short* __restrict__ wh, const unsigned short* __restrict__ wl,
    const unsigned short* __restrict__ xh, const unsigned short* __restrict__ xl,
    const float* __restrict__ tb1, const float* __restrict__ db1,
    float* __restrict__ hb, float* __restrict__ cb, float* __restrict__ nb) {
  __shared__ __align__(16) unsigned short Ah[128][40], Al[128][40];
  __shared__ __align__(16) unsigned short Bh[128][40], Bl[128][40];
  int mt = blockIdx.x;
  int b = mt >> 4;
  int t0 = (mt & 15) * 128;
  int o0 = blockIdx.y * 128;
  int tid = threadIdx.x;
  int w = tid >> 6, lane = tid & 63, quad = lane >> 4, l15 = lane & 15;
  int wm = (w >> 1) * 64, wn = (w & 1) * 64;
  floatx4 acc[4][4];
#pragma unroll
  for (int i = 0; i < 4; ++i)
#pragma unroll
    for (int j = 0; j < 4; ++j) acc[i][j] = (floatx4){0.f, 0.f, 0.f, 0.f};

  const unsigned short* xhb = xh + ((size_t)b * Tt + t0) * Cc;
  const unsigned short* xlb = xl + ((size_t)b * Tt + t0) * Cc;
  int sr = tid >> 1;
  int sq = (tid & 1) * 2;
  for (int kc = 0; kc < Cc; kc += 32) {
    __syncthreads();
    {
      const unsigned short* am = wh + (size_t)(o0 + sr) * Cc + kc + sq * 8;
      *(uint4*)&Ah[sr][sq * 8] = *(const uint4*)am;
      *(uint4*)&Ah[sr][sq * 8 + 8] = *(const uint4*)(am + 8);
      const unsigned short* al = wl + (size_t)(o0 + sr) * Cc + kc + sq * 8;
      *(uint4*)&Al[sr][sq * 8] = *(const uint4*)al;
      *(uint4*)&Al[sr][sq * 8 + 8] = *(const uint4*)(al + 8);
      const unsigned short* bm = xhb + (size_t)sr * Cc + kc + sq * 8;
      *(uint4*)&Bh[sr][sq * 8] = *(const uint4*)bm;
      *(uint4*)&Bh[sr][sq * 8 + 8] = *(const uint4*)(bm + 8);
      const unsigned short* bl = xlb + (size_t)sr * Cc + kc + sq * 8;
      *(uint4*)&Bl[sr][sq * 8] = *(const uint4*)bl;
      *(uint4*)&Bl[sr][sq * 8 + 8] = *(const uint4*)(bl + 8);
    }
    __syncthreads();
    int ka = quad * 8;
    short8 a_h[4], a_l[4], b_h[4], b_l[4];
#pragma unroll
    for (int f = 0; f < 4; ++f) {
      a_h[f] = *(const short8*)&Ah[wm + f * 16 + l15][ka];
      a_l[f] = *(const short8*)&Al[wm + f * 16 + l15][ka];
      b_h[f] = *(const short8*)&Bh[wn + f * 16 + l15][ka];
      b_l[f] = *(const short8*)&Bl[wn + f * 16 + l15][ka];
    }
#pragma unroll
    for (int fm = 0; fm < 4; ++fm)
#pragma unroll
      for (int fn = 0; fn < 4; ++fn) {
        acc[fm][fn] = __builtin_amdgcn_mfma_f32_16x16x32_bf16(a_h[fm], b_h[fn], acc[fm][fn], 0, 0, 0);
        acc[fm][fn] = __builtin_amdgcn_mfma_f32_16x16x32_bf16(a_h[fm], b_l[fn], acc[fm][fn], 0, 0, 0);
        acc[fm][fn] = __builtin_amdgcn_mfma_f32_16x16x32_bf16(a_l[fm], b_h[fn], acc[fm][fn], 0, 0, 0);
      }
  }
  int range = o0 >> 8;                 // 0: h(gelu,tb1)  1: ctr(db1)  2: nbr
  float* dst = (range == 0) ? hb : (range == 1) ? cb : nb;
  const float* bias = (range == 0) ? tb1 : (range == 1) ? db1 : nullptr;
  int ol0 = o0 & 255;
#pragma unroll
  for (int fm = 0; fm < 4; ++fm) {
    int o = ol0 + wm + fm * 16 + quad * 4;
#pragma unroll
    for (int r = 0; r < 4; ++r) {
      float bv = bias ? bias[o + r] : 0.f;
      size_t rowoff = ((size_t)b * Cc + o + r) * Tt + t0;
#pragma unroll
      for (int fn = 0; fn < 4; ++fn) {
        int t = wn + fn * 16 + l15;
        float v = acc[fm][fn][r] + bv;
        if (range == 0) v = gelu_f(v);
        dst[rowoff + t] = v;
      }
    }
  }
}

// score GEMM, 2 batches per dispatch via z
__global__ __launch_bounds__(256) void score_gemm(
    const unsigned short* __restrict__ xh, const unsigned short* __restrict__ xl,
    const float* __restrict__ xx, float* __restrict__ S, int bbase) {
  __shared__ __align__(16) unsigned short Ah[128][40], Al[128][40];
  __shared__ __align__(16) unsigned short Bh[128][40], Bl[128][40];
  int lb = blockIdx.z;
  int b = bbase + lb;
  int m0 = blockIdx.y * 128, n0 = blockIdx.x * 128;
  int tid = threadIdx.x;
  int w = tid >> 6, lane = tid & 63, quad = lane >> 4, l15 = lane & 15;
  int wm = (w >> 1) * 64, wn = (w & 1) * 64;
  const unsigned short* xhb = xh + (size_t)b * Tt * Cc;
  const unsigned short* xlb = xl + (size_t)b * Tt * Cc;
  const float* xxb = xx + (size_t)b * Tt;
  float* Sb = S + (size_t)lb * Tt * Tt;
  floatx4 acc[4][4];
#pragma unroll
  for (int i = 0; i < 4; ++i)
#pragma unroll
    for (int j = 0; j < 4; ++j) acc[i][j] = (floatx4){0.f, 0.f, 0.f, 0.f};

  int sr = tid >> 1;
  int sq = (tid & 1) * 2;
  for (int kc = 0; kc < Cc; kc += 32) {
    __syncthreads();
    {
      const unsigned short* am = xhb + (size_t)(m0 + sr) * Cc + kc + sq * 8;
      *(uint4*)&Ah[sr][sq * 8] = *(const uint4*)am;
      *(uint4*)&Ah[sr][sq * 8 + 8] = *(const uint4*)(am + 8);
      const unsigned short* al = xlb + (size_t)(m0 + sr) * Cc + kc + sq * 8;
      *(uint4*)&Al[sr][sq * 8] = *(const uint4*)al;
      *(uint4*)&Al[sr][sq * 8 + 8] = *(const uint4*)(al + 8);
      const unsigned short* bm = xhb + (size_t)(n0 + sr) * Cc + kc + sq * 8;
      *(uint4*)&Bh[sr][sq * 8] = *(const uint4*)bm;
      *(uint4*)&Bh[sr][sq * 8 + 8] = *(const uint4*)(bm + 8);
      const unsigned short* bl = xlb + (size_t)(n0 + sr) * Cc + kc + sq * 8;
      *(uint4*)&Bl[sr][sq * 8] = *(const uint4*)bl;
      *(uint4*)&Bl[sr][sq * 8 + 8] = *(const uint4*)(bl + 8);
    }
    __syncthreads();
    int ka = quad * 8;
    short8 a_h[4], a_l[4], b_h[4], b_l[4];
#pragma unroll
    for (int f = 0; f < 4; ++f) {
      a_h[f] = *(const short8*)&Ah[wm + f * 16 + l15][ka];
      a_l[f] = *(const short8*)&Al[wm + f * 16 + l15][ka];
      b_h[f] = *(const short8*)&Bh[wn + f * 16 + l15][ka];
      b_l[f] = *(const short8*)&Bl[wn + f * 16 + l15][ka];
    }
#pragma unroll
    for (int fm = 0; fm < 4; ++fm)
#pragma unroll
      for (int fn = 0; fn < 4; ++fn) {
        acc[fm][fn] = __builtin_amdgcn_mfma_f32_16x16x32_bf16(a_h[fm], b_h[fn], acc[fm][fn], 0, 0, 0);
        acc[fm][fn] = __builtin_amdgcn_mfma_f32_16x16x32_bf16(a_h[fm], b_l[fn], acc[fm][fn], 0, 0, 0);
        acc[fm][fn] = __builtin_amdgcn_mfma_f32_16x16x32_bf16(a_l[fm], b_h[fn], acc[fm][fn], 0, 0, 0);
      }
  }
#pragma unroll
  for (int fn = 0; fn < 4; ++fn) {
    int n = n0 + wn + fn * 16 + l15;
    float xv = xxb[n];
#pragma unroll
    for (int fm = 0; fm < 4; ++fm) {
      int m = m0 + wm + fm * 16 + quad * 4;
#pragma unroll
      for (int r = 0; r < 4; ++r)
        Sb[(size_t)(m + r) * Tt + n] = fmaf(2.f, acc[fm][fn][r], -xv);
    }
  }
}

// top-10 scan, 2 batches via z; wave per row, 8 rows per block
__global__ __launch_bounds__(512) void topk_scan(
    const float* __restrict__ S, int* __restrict__ idx10, int bbase) {
  int lb = blockIdx.z;
  int m = blockIdx.x * 8 + (threadIdx.x >> 6);
  int lane = threadIdx.x & 63;
  const float* row = S + ((size_t)lb * Tt + m) * Tt;
  float s[NTOP]; int idl[NTOP];
#pragma unroll
  for (int j = 0; j < NTOP; ++j) { s[j] = -INFINITY; idl[j] = 0x7fffffff; }
  for (int c0 = lane * 4; c0 < Tt; c0 += 256) {
    float4 v = *(const float4*)(row + c0);
    float cand[4] = {v.x, v.y, v.z, v.w};
#pragma unroll
    for (int e = 0; e < 4; ++e) {
      float sc = cand[e];
      if (sc > s[NTOP - 1]) {
        s[NTOP - 1] = sc; idl[NTOP - 1] = c0 + e;
#pragma unroll
        for (int j = NTOP - 1; j > 0; --j) {
          if (s[j] > s[j - 1]) {
            float ts = s[j]; s[j] = s[j - 1]; s[j - 1] = ts;
            int ti = idl[j]; idl[j] = idl[j - 1]; idl[j - 1] = ti;
          }
        }
      }
    }
  }
  int ptr = 0;
  for (int r = 0; r < NTOP; ++r) {
    float cs = (ptr < NTOP) ? s[ptr] : -INFINITY;
    int cid = (ptr < NTOP) ? idl[ptr] : 0x7fffffff;
    float bs = cs; int bi = cid;
#pragma unroll
    for (int off = 1; off < 64; off <<= 1) {
      float os = __shfl_xor(bs, off);
      int oi = __shfl_xor(bi, off);
      if (os > bs || (os == bs && oi < bi)) { bs = os; bi = oi; }
    }
    if (cid == bi) ptr++;
    if (lane == 0) idx10[((size_t)(bbase + lb) * Tt + m) * NTOP + r] = bi;
  }
}

// fp64 rescore of the NTOP shortlist, emit exact top-7
__global__ __launch_bounds__(64) void knn_rescore(
    const float* __restrict__ xT, const int* __restrict__ idx10,
    int* __restrict__ idxout) {
  int t = blockIdx.x;
  int b = blockIdx.y;
  int lane = threadIdx.x;
  const float* xTb = xT + (size_t)b * Tt * Cc;
  const float* xm = xTb + (size_t)t * Cc;
  double sc = -1e300;
  int cid = 0x7fffffff;
  if (lane < NTOP) {
    int j = idx10[((size_t)b * Tt + t) * NTOP + lane];
    const float* xn = xTb + (size_t)j * Cc;
    double dot = 0.0, nn = 0.0;
    for (int c = 0; c < Cc; c += 4) {
      float4 a = *(const float4*)(xm + c);
      float4 v = *(const float4*)(xn + c);
      dot += (double)a.x * v.x + (double)a.y * v.y + (double)a.z * v.z + (double)a.w * v.w;
      nn  += (double)v.x * v.x + (double)v.y * v.y + (double)v.z * v.z + (double)v.w * v.w;
    }
    sc = 2.0 * dot - nn;
    cid = j;
  }
  for (int r = 0; r < Kk; ++r) {
    double bs = sc; int bi = cid;
#pragma unroll
    for (int off = 1; off < 64; off <<= 1) {
      double os = __shfl_xor(bs, off);
      int oi = __shfl_xor(bi, off);
      if (os > bs || (os == bs && oi < bi)) { bs = os; bi = oi; }
    }
    if (cid == bi) { sc = -1e300; cid = 0x7fffffff; }
    if (lane == 0) idxout[((size_t)b * Tt + t) * Kk + r] = bi;
  }
}

// Fused graph tail + temporal conv, v4 = R0 structure + scalar fma.
//  - R0's 256-thread / 64-t tile / half-wave layout (ol=tid>>5, tl2=(tid&31)*2)
//    is kept: lanes 32-63 read the SAME LDS addresses as lanes 0-31 (broadcast,
//    free) — R2 proved losing this makes the kernel LDS-throughput-bound.
//  - Only change vs R0: scalar fmaf chains instead of packed floatx2 fma.
//    v_pk_fma_f32 is half-rate on CDNA4 (fp32 peak = 1 fma/lane/cy = scalar
//    rate), so packed saves nothing and costs ~10 v_movs per (ci,kin) to build
//    misaligned {r6[dt],r6[dt+1]} register pairs. Scalar: same FMA cycles,
//    zero repack.
//  - Per-element accumulation order (bias -> ci -> kin -> dk -> dt, then max
//    over k, then acct+m+x) is IDENTICAL to R0 ==> layer-1 x1 bit-identical
//    ==> layer-2 KNN unchanged (R10 forensics).
// FAST=0: exact erff (layer 1 -> x1 -> layer-2 KNN must be bit-stable).
// FAST=1: rational erf (layer 2 -> only final output).
template <int FAST>
__global__ __launch_bounds__(256) void graph_tail(
    const float* __restrict__ h, const float* __restrict__ ctr,
    const float* __restrict__ nbrT, const int* __restrict__ idx,
    const float* __restrict__ tw2, const float* __restrict__ tb2,
    const float* __restrict__ dw2, const float* __restrict__ db2,
    const float* __restrict__ xin, float* __restrict__ xout) {
  __shared__ __align__(16) float gt[CG][Kk][68];   // 14.9 KB
  __shared__ __align__(16) float ht[CG][68];       // 2.2 KB
  __shared__ __align__(16) float ct[CG][68];       // 2.2 KB
  __shared__ int jt[Kk * 68];                      // 1.9 KB, [k][tl]
  int t0 = blockIdx.x * 64;
  int g = blockIdx.y;
  int b = blockIdx.z;
  int tid = threadIdx.x;
  const float* hg   = h   + ((size_t)b * Cc + g * CG) * Tt;
  const float* ctrg = ctr + ((size_t)b * Cc + g * CG) * Tt;
  const float* nbT  = nbrT + (size_t)b * Tt * Cc + g * CG;

  {
    const int* ib = idx + ((size_t)b * Tt + t0 - 2) * Kk;
    for (int p = tid; p < Kk * 68; p += 256) {
      int k = p / 68, tl = p - k * 68;
      int tg = t0 - 2 + tl;
      jt[p] = (tg >= 0 && tg < Tt) ? ib[tl * Kk + k] : 0;
    }
    for (int e = tid; e < CG * 68; e += 256) {
      int ci = e / 68, tl = e - ci * 68;
      int tg = t0 - 2 + tl;
      int valid = (tg >= 0 && tg < Tt);
      ht[ci][tl] = valid ? hg[(size_t)ci * Tt + tg] : 0.f;
      ct[ci][tl] = valid ? ctrg[(size_t)ci * Tt + tg] : 0.f;
    }
  }
  __syncthreads();
  for (int p = tid; p < Kk * 68; p += 256) {
    int k = p / 68, tl = p - k * 68;
    int tg = t0 - 2 + tl;
    int valid = (tg >= 0 && tg < Tt);
    int j = jt[p];
    const float* np = nbT + (size_t)j * Cc;
    float4 n0 = *(const float4*)np;
    float4 n1 = *(const float4*)(np + 4);
    float ch[8] = {n0.x, n0.y, n0.z, n0.w, n1.x, n1.y, n1.z, n1.w};
#pragma unroll
    for (int ci = 0; ci < CG; ++ci) {
      float pre = ct[ci][tl] + ch[ci];
      float v = FAST ? gelu_fast(pre) : gelu_f(pre);
      gt[ci][k][tl] = valid ? v : 0.f;
    }
  }
  __syncthreads();

  int ol = tid >> 5, tl2 = (tid & 31) * 2;
  int o = g * CG + ol;

  // temporal grouped conv1d k=5
  const float* w2 = tw2 + (size_t)o * CG * 5;
  float bt = tb2[o];
  float at0 = bt, at1 = bt;
  for (int ci = 0; ci < CG; ++ci) {
    const float* hr = &ht[ci][tl2];
    float rr[6];
#pragma unroll
    for (int q = 0; q < 6; ++q) rr[q] = hr[q];
#pragma unroll
    for (int dt = 0; dt < 5; ++dt) {
      float wvv = w2[ci * 5 + dt];
      at0 = fmaf(wvv, rr[dt], at0);
      at1 = fmaf(wvv, rr[dt + 1], at1);
    }
  }

  // grouped dconv2d 5x5 over (t,k)
  const float* wp = dw2 + (size_t)o * CG * 25;
  float bv = db2[o];
  float a0[Kk], a1[Kk];
#pragma unroll
  for (int k = 0; k < Kk; ++k) { a0[k] = bv; a1[k] = bv; }

  for (int ci = 0; ci < CG; ++ci) {
    float w[25];
#pragma unroll
    for (int i = 0; i < 25; ++i) w[i] = wp[ci * 25 + i];
#pragma unroll
    for (int kin = 0; kin < Kk; ++kin) {
      const float* gr = &gt[ci][kin][tl2];
      float rr[6];
#pragma unroll
      for (int q = 0; q < 6; ++q) rr[q] = gr[q];
#pragma unroll
      for (int dk = 0; dk < 5; ++dk) {
        int k = kin + 2 - dk;
        if (k < 0 || k >= Kk) continue;
#pragma unroll
        for (int dt = 0; dt < 5; ++dt) {
          float wvv = w[dt * 5 + dk];
          a0[k] = fmaf(wvv, rr[dt], a0[k]);
          a1[k] = fmaf(wvv, rr[dt + 1], a1[k]);
        }
      }
    }
  }
  float m0 = a0[0], m1 = a1[0];
#pragma unroll
  for (int k = 1; k < Kk; ++k) { m0 = fmaxf(m0, a0[k]); m1 = fmaxf(m1, a1[k]); }
  size_t off = ((size_t)b * Cc + o) * Tt + t0 + tl2;
  floatx2 xv = *(const floatx2*)&xin[off];
  floatx2 r;
  r.x = at0 + m0 + xv.x;
  r.y = at1 + m1 + xv.y;
  *(floatx2*)&xout[off] = r;
}

extern "C" void kernel_launch(void* const* d_in, const int* in_sizes, int n_in,
                              void* d_out, int out_size, void* d_ws, size_t ws_size,
                              hipStream_t stream) {
  const float* x0  = (const float*)d_in[0];
  const float* tw1 = (const float*)d_in[1];
  const float* tb1 = (const float*)d_in[2];
  const float* tw2 = (const float*)d_in[3];
  const float* tb2 = (const float*)d_in[4];
  const float* dw1 = (const float*)d_in[5];
  const float* db1 = (const float*)d_in[6];
  const float* dw2 = (const float*)d_in[7];
  const float* db2 = (const float*)d_in[8];
  float* out = (float*)d_out;

  float* ws = (float*)d_ws;
  const size_t NCT = (size_t)Bq * Cc * Tt;      // 2M elements
  float* x1   = ws;                             // layer-1 output   [B,C,T]
  float* hbuf = x1 + NCT;                       // h                [B,C,T]
  float* cbuf = hbuf + NCT;                     // ctr              [B,C,T]
  float* xT   = cbuf + NCT;                     // xT, then nbr     [B,T,C]
  unsigned short* xh = (unsigned short*)(xT + NCT);   // [B,T,C] bf16 hi
  unsigned short* xl = xh + NCT;                      // bf16 lo
  unsigned short* wh = xl + NCT;                      // weights hi [768][256]
  unsigned short* wl = wh + (size_t)NO * Cc;
  float* S    = (float*)(wl + (size_t)NO * Cc); // scores, 2 batches [2,T,T] 32MB
  float* xx   = S + 2 * (size_t)Tt * Tt;        // squared norms    [B,T]
  int* idxb   = (int*)(xx + (size_t)Bq * Tt);   // top-7            [B,T,K]
  int* idx10  = idxb + (size_t)Bq * Tt * Kk;    // top-10           [B,T,NTOP]
  float* nbrT = (float*)(idx10 + (size_t)Bq * Tt * NTOP);  // nbr^T [B,T,C] 8MB
  float* nbr  = xT;                             // nbr overwrites xT after rescore

  for (int i = 0; i < Ll; ++i) {
    const float* xin = (i == 0) ? x0 : x1;
    float* xout = (i == Ll - 1) ? out : x1;

    transpose_x<<<dim3(Tt/32, Cc/32, Bq), dim3(32, 8), 0, stream>>>(xin, xT, xh, xl);
    sqnorm_xt<<<dim3(Tt/8, Bq), 512, 0, stream>>>(xT, xx);
    for (int bp = 0; bp < Bq; bp += 2) {
      score_gemm<<<dim3(16, 16, 2), 256, 0, stream>>>(xh, xl, xx, S, bp);
      topk_scan<<<dim3(Tt/8, 1, 2), 512, 0, stream>>>(S, idx10, bp);
    }
    knn_rescore<<<dim3(Tt, Bq), 64, 0, stream>>>(xT, idx10, idxb);

    if (i == 0) {
      // Layer 1: exact fp32 pointwise convs (x1 feeds layer-2 KNN; R6/R7/R10 forensics)
      pw_conv8_all<<<dim3(Tt/1024, 96, Bq), 256, 0, stream>>>(
          xin, tw1 + (size_t)i * Cc * Cc, tb1 + (size_t)i * Cc,
          dw1 + (size_t)i * Cc * 2 * Cc, db1 + (size_t)i * Cc,
          hbuf, cbuf, nbr);
    } else {
      // Layer 2: split-bf16 MFMA GEMM — output feeds only the final result.
      wsplit<<<dim3(NO), 256, 0, stream>>>(
          tw1 + (size_t)i * Cc * Cc, dw1 + (size_t)i * Cc * 2 * Cc, wh, wl);
      pw_gemm<<<dim3(64, NO/128), 256, 0, stream>>>(
          wh, wl, xh, xl, tb1 + (size_t)i * Cc, db1 + (size_t)i * Cc,
          hbuf, cbuf, nbr);
    }
    // nbr -> nbrT [B,T,C] for transaction-efficient gathers in graph_tail
    transpose_f<<<dim3(Tt/32, Cc/32, Bq), dim3(32, 8), 0, stream>>>(nbr, nbrT);
    if (i == 0) {
      graph_tail<0><<<dim3(Tt/64, Cc/CG, Bq), 256, 0, stream>>>(
          hbuf, cbuf, nbrT, idxb, tw2 + (size_t)i * Cc * CG * 5, tb2 + (size_t)i * Cc,
          dw2 + (size_t)i * Cc * CG * 25, db2 + (size_t)i * Cc, xin, xout);
    } else {
      graph_tail<1><<<dim3(Tt/64, Cc/CG, Bq), 256, 0, stream>>>(
          hbuf, cbuf, nbrT, idxb, tw2 + (size_t)i * Cc * CG * 5, tb2 + (size_t)i * Cc,
          dw2 + (size_t)i * Cc * CG * 25, db2 + (size_t)i * Cc, xin, xout);
    }
  }
}

// Round 4
// 556.125 us; speedup vs baseline: 1.2663x; 1.2663x over previous
//
#include <hip/hip_runtime.h>
#include <math.h>

#define Bq 4
#define Cc 256
#define Tt 2048
#define Kk 7
#define NTOP 10
#define CG 8
#define Ll 2
#define NO 768   // fused pointwise outputs: 256 h | 256 ctr | 256 nbr

typedef __attribute__((ext_vector_type(8))) short short8;
typedef __attribute__((ext_vector_type(4))) float floatx4;
typedef __attribute__((ext_vector_type(2))) float floatx2;

__device__ __forceinline__ float gelu_f(float v) {
  return 0.5f * v * (1.0f + erff(v * 0.70710678118654752440f));
}

// A&S 7.1.26 rational erf (~1e-6 eff err in fp32). SAFE ONLY on paths that do
// not feed a later top-k: R10 proved a ~1e-6 x1 perturbation flips layer-2 KNN.
__device__ __forceinline__ float erf_fast(float x) {
  float ax = fabsf(x);
  float t = __builtin_amdgcn_rcpf(fmaf(0.3275911f, ax, 1.0f));
  float y = t * (0.254829592f + t * (-0.284496736f + t * (1.421413741f +
            t * (-1.453152027f + t * 1.061405429f))));
  float r = 1.0f - y * __expf(-ax * ax);
  return copysignf(r, x);
}
__device__ __forceinline__ float gelu_fast(float v) {
  return 0.5f * v * (1.0f + erf_fast(v * 0.70710678118654752440f));
}

// xT[b][t][c] = x[b][c][t]; also emits bf16 hi/lo split
__global__ void transpose_x(const float* __restrict__ x, float* __restrict__ xT,
                            unsigned short* __restrict__ xh,
                            unsigned short* __restrict__ xl) {
  __shared__ float tile[32][33];
  int b = blockIdx.z;
  int t0 = blockIdx.x * 32, c0 = blockIdx.y * 32;
  int tx = threadIdx.x, ty = threadIdx.y;
  const float* xb = x + (size_t)b * Cc * Tt;
  for (int r = ty; r < 32; r += 8)
    tile[r][tx] = xb[(size_t)(c0 + r) * Tt + t0 + tx];
  __syncthreads();
  size_t base = (size_t)b * Tt * Cc;
  for (int r = ty; r < 32; r += 8) {
    float v = tile[tx][r];
    size_t o = base + (size_t)(t0 + r) * Cc + c0 + tx;
    xT[o] = v;
    unsigned int u = __float_as_uint(v);
    unsigned short h = (unsigned short)((u + 0x7fffu + ((u >> 16) & 1u)) >> 16);
    float f = v - __uint_as_float((unsigned int)h << 16);
    unsigned int ul = __float_as_uint(f);
    xh[o] = h;
    xl[o] = (unsigned short)((ul + 0x7fffu + ((ul >> 16) & 1u)) >> 16);
  }
}

// plain fp32 transpose: dst[b][t][c] = src[b][c][t]  (for nbr -> nbrT)
__global__ void transpose_f(const float* __restrict__ src, float* __restrict__ dst) {
  __shared__ float tile[32][33];
  int b = blockIdx.z;
  int t0 = blockIdx.x * 32, c0 = blockIdx.y * 32;
  int tx = threadIdx.x, ty = threadIdx.y;
  const float* sb = src + (size_t)b * Cc * Tt;
  for (int r = ty; r < 32; r += 8)
    tile[r][tx] = sb[(size_t)(c0 + r) * Tt + t0 + tx];
  __syncthreads();
  float* db = dst + (size_t)b * Tt * Cc;
  for (int r = ty; r < 32; r += 8)
    db[(size_t)(t0 + r) * Cc + c0 + tx] = tile[tx][r];
}

// squared norms from xT; wave per row t, 8 rows per block
__global__ __launch_bounds__(512) void sqnorm_xt(
    const float* __restrict__ xT, float* __restrict__ xx) {
  int b = blockIdx.y;
  int t = blockIdx.x * 8 + (threadIdx.x >> 6);
  int lane = threadIdx.x & 63;
  const float* row = xT + ((size_t)b * Tt + t) * Cc;
  float4 v = *(const float4*)(row + lane * 4);
  float acc = v.x * v.x + v.y * v.y + v.z * v.z + v.w * v.w;
#pragma unroll
  for (int off = 1; off < 64; off <<= 1) acc += __shfl_xor(acc, off);
  if (lane == 0) xx[(size_t)b * Tt + t] = acc;
}

// fp32 pointwise convs, all 3 ranges in one launch (layer-1 exact path).
// Thread = 8 outputs x 4 tokens, float4 x-loads (32 FMA per load vs 8 before).
// Per-(o,t) fmaf chain remains bias -> ascending c  ==> bit-identical to R12.
__global__ __launch_bounds__(256) void pw_conv8_all(
    const float* __restrict__ x, const float* __restrict__ tw1,
    const float* __restrict__ tb1, const float* __restrict__ dw1,
    const float* __restrict__ db1, float* __restrict__ hb,
    float* __restrict__ cb, float* __restrict__ nb) {
  int tid = threadIdx.x;
  int wv = tid >> 6, lane = tid & 63;
  int t = blockIdx.x * 1024 + wv * 256 + lane * 4;   // 4 consecutive tokens
  int oy = blockIdx.y;
  int b = blockIdx.z;
  int range = oy >> 5;            // 0: h  1: ctr  2: nbr
  int o0 = (oy & 31) * 8;
  const float* W; int wstride, woff; const float* bias; float* dst; int dg;
  if (range == 0)      { W = tw1; wstride = Cc;     woff = 0;  bias = tb1;     dst = hb; dg = 1; }
  else if (range == 1) { W = dw1; wstride = 2 * Cc; woff = Cc; bias = db1;     dst = cb; dg = 0; }
  else                 { W = dw1; wstride = 2 * Cc; woff = 0;  bias = nullptr; dst = nb; dg = 0; }
  const float* xp = x + (size_t)b * Cc * Tt + t;
  const float* wp = W + (size_t)o0 * wstride + woff;
  float acc[8][4];
#pragma unroll
  for (int j = 0; j < 8; ++j) {
    float bv = bias ? bias[o0 + j] : 0.f;
#pragma unroll
    for (int e = 0; e < 4; ++e) acc[j][e] = bv;
  }
  for (int c = 0; c < Cc; c += 4) {
    float4 xv0 = *(const float4*)(xp + (size_t)c * Tt);
    float4 xv1 = *(const float4*)(xp + (size_t)(c + 1) * Tt);
    float4 xv2 = *(const float4*)(xp + (size_t)(c + 2) * Tt);
    float4 xv3 = *(const float4*)(xp + (size_t)(c + 3) * Tt);
    float x0[4] = {xv0.x, xv0.y, xv0.z, xv0.w};
    float x1[4] = {xv1.x, xv1.y, xv1.z, xv1.w};
    float x2[4] = {xv2.x, xv2.y, xv2.z, xv2.w};
    float x3[4] = {xv3.x, xv3.y, xv3.z, xv3.w};
#pragma unroll
    for (int j = 0; j < 8; ++j) {
      const float* wr = wp + (size_t)j * wstride + c;   // wave-uniform -> s_load
      float w0 = wr[0], w1 = wr[1], w2 = wr[2], w3 = wr[3];
#pragma unroll
      for (int e = 0; e < 4; ++e) {
        float a = acc[j][e];
        a = fmaf(w0, x0[e], a);
        a = fmaf(w1, x1[e], a);
        a = fmaf(w2, x2[e], a);
        a = fmaf(w3, x3[e], a);
        acc[j][e] = a;
      }
    }
  }
#pragma unroll
  for (int j = 0; j < 8; ++j) {
    float4 r;
    float* rp = (float*)&r;
#pragma unroll
    for (int e = 0; e < 4; ++e) {
      float v = acc[j][e];
      if (dg) v = gelu_f(v);
      rp[e] = v;
    }
    *(float4*)&dst[((size_t)b * Cc + o0 + j) * Tt + t] = r;
  }
}

// concat weights [768][256] -> bf16 hi/lo (layer-2 only)
__global__ __launch_bounds__(256) void wsplit(
    const float* __restrict__ tw1, const float* __restrict__ dw1,
    unsigned short* __restrict__ wh, unsigned short* __restrict__ wl) {
  int o = blockIdx.x;
  int c = threadIdx.x;
  float v;
  if (o < 256) v = tw1[(size_t)o * Cc + c];
  else if (o < 512) v = dw1[(size_t)(o - 256) * (2 * Cc) + Cc + c];
  else v = dw1[(size_t)(o - 512) * (2 * Cc) + c];
  unsigned int u = __float_as_uint(v);
  unsigned short h = (unsigned short)((u + 0x7fffu + ((u >> 16) & 1u)) >> 16);
  float f = v - __uint_as_float((unsigned int)h << 16);
  unsigned int ul = __float_as_uint(f);
  wh[(size_t)o * Cc + c] = h;
  wl[(size_t)o * Cc + c] = (unsigned short)((ul + 0x7fffu + ((ul >> 16) & 1u)) >> 16);
}

// fused pointwise GEMM (layer-2 only)
__global__ __launch_bounds__(256) void pw_gemm(
    const unsigned short* __restrict__ wh, const unsigned short* __restrict__ wl,
    const unsigned short* __restrict__ xh, const unsigned short* __restrict__ xl,
    const float* __restrict__ tb1, const float* __restrict__ db1,
    float* __restrict__ hb, float* __restrict__ cb, float* __restrict__ nb) {
  __shared__ __align__(16) unsigned short Ah[128][40], Al[128][40];
  __shared__ __align__(16) unsigned short Bh[128][40], Bl[128][40];
  int mt = blockIdx.x;
  int b = mt >> 4;
  int t0 = (mt & 15) * 128;
  int o0 = blockIdx.y * 128;
  int tid = threadIdx.x;
  int w = tid >> 6, lane = tid & 63, quad = lane >> 4, l15 = lane & 15;
  int wm = (w >> 1) * 64, wn = (w & 1) * 64;
  floatx4 acc[4][4];
#pragma unroll
  for (int i = 0; i < 4; ++i)
#pragma unroll
    for (int j = 0; j < 4; ++j) acc[i][j] = (floatx4){0.f, 0.f, 0.f, 0.f};

  const unsigned short* xhb = xh + ((size_t)b * Tt + t0) * Cc;
  const unsigned short* xlb = xl + ((size_t)b * Tt + t0) * Cc;
  int sr = tid >> 1;
  int sq = (tid & 1) * 2;
  for (int kc = 0; kc < Cc; kc += 32) {
    __syncthreads();
    {
      const unsigned short* am = wh + (size_t)(o0 + sr) * Cc + kc + sq * 8;
      *(uint4*)&Ah[sr][sq * 8] = *(const uint4*)am;
      *(uint4*)&Ah[sr][sq * 8 + 8] = *(const uint4*)(am + 8);
      const unsigned short* al = wl + (size_t)(o0 + sr) * Cc + kc + sq * 8;
      *(uint4*)&Al[sr][sq * 8] = *(const uint4*)al;
      *(uint4*)&Al[sr][sq * 8 + 8] = *(const uint4*)(al + 8);
      const unsigned short* bm = xhb + (size_t)sr * Cc + kc + sq * 8;
      *(uint4*)&Bh[sr][sq * 8] = *(const uint4*)bm;
      *(uint4*)&Bh[sr][sq * 8 + 8] = *(const uint4*)(bm + 8);
      const unsigned short* bl = xlb + (size_t)sr * Cc + kc + sq * 8;
      *(uint4*)&Bl[sr][sq * 8] = *(const uint4*)bl;
      *(uint4*)&Bl[sr][sq * 8 + 8] = *(const uint4*)(bl + 8);
    }
    __syncthreads();
    int ka = quad * 8;
    short8 a_h[4], a_l[4], b_h[4], b_l[4];
#pragma unroll
    for (int f = 0; f < 4; ++f) {
      a_h[f] = *(const short8*)&Ah[wm + f * 16 + l15][ka];
      a_l[f] = *(const short8*)&Al[wm + f * 16 + l15][ka];
      b_h[f] = *(const short8*)&Bh[wn + f * 16 + l15][ka];
      b_l[f] = *(const short8*)&Bl[wn + f * 16 + l15][ka];
    }
#pragma unroll
    for (int fm = 0; fm < 4; ++fm)
#pragma unroll
      for (int fn = 0; fn < 4; ++fn) {
        acc[fm][fn] = __builtin_amdgcn_mfma_f32_16x16x32_bf16(a_h[fm], b_h[fn], acc[fm][fn], 0, 0, 0);
        acc[fm][fn] = __builtin_amdgcn_mfma_f32_16x16x32_bf16(a_h[fm], b_l[fn], acc[fm][fn], 0, 0, 0);
        acc[fm][fn] = __builtin_amdgcn_mfma_f32_16x16x32_bf16(a_l[fm], b_h[fn], acc[fm][fn], 0, 0, 0);
      }
  }
  int range = o0 >> 8;                 // 0: h(gelu,tb1)  1: ctr(db1)  2: nbr
  float* dst = (range == 0) ? hb : (range == 1) ? cb : nb;
  const float* bias = (range == 0) ? tb1 : (range == 1) ? db1 : nullptr;
  int ol0 = o0 & 255;
#pragma unroll
  for (int fm = 0; fm < 4; ++fm) {
    int o = ol0 + wm + fm * 16 + quad * 4;
#pragma unroll
    for (int r = 0; r < 4; ++r) {
      float bv = bias ? bias[o + r] : 0.f;
      size_t rowoff = ((size_t)b * Cc + o + r) * Tt + t0;
#pragma unroll
      for (int fn = 0; fn < 4; ++fn) {
        int t = wn + fn * 16 + l15;
        float v = acc[fm][fn][r] + bv;
        if (range == 0) v = gelu_f(v);
        dst[rowoff + t] = v;
      }
    }
  }
}

// score GEMM, 2 batches per dispatch via z
__global__ __launch_bounds__(256) void score_gemm(
    const unsigned short* __restrict__ xh, const unsigned short* __restrict__ xl,
    const float* __restrict__ xx, float* __restrict__ S, int bbase) {
  __shared__ __align__(16) unsigned short Ah[128][40], Al[128][40];
  __shared__ __align__(16) unsigned short Bh[128][40], Bl[128][40];
  int lb = blockIdx.z;
  int b = bbase + lb;
  int m0 = blockIdx.y * 128, n0 = blockIdx.x * 128;
  int tid = threadIdx.x;
  int w = tid >> 6, lane = tid & 63, quad = lane >> 4, l15 = lane & 15;
  int wm = (w >> 1) * 64, wn = (w & 1) * 64;
  const unsigned short* xhb = xh + (size_t)b * Tt * Cc;
  const unsigned short* xlb = xl + (size_t)b * Tt * Cc;
  const float* xxb = xx + (size_t)b * Tt;
  float* Sb = S + (size_t)lb * Tt * Tt;
  floatx4 acc[4][4];
#pragma unroll
  for (int i = 0; i < 4; ++i)
#pragma unroll
    for (int j = 0; j < 4; ++j) acc[i][j] = (floatx4){0.f, 0.f, 0.f, 0.f};

  int sr = tid >> 1;
  int sq = (tid & 1) * 2;
  for (int kc = 0; kc < Cc; kc += 32) {
    __syncthreads();
    {
      const unsigned short* am = xhb + (size_t)(m0 + sr) * Cc + kc + sq * 8;
      *(uint4*)&Ah[sr][sq * 8] = *(const uint4*)am;
      *(uint4*)&Ah[sr][sq * 8 + 8] = *(const uint4*)(am + 8);
      const unsigned short* al = xlb + (size_t)(m0 + sr) * Cc + kc + sq * 8;
      *(uint4*)&Al[sr][sq * 8] = *(const uint4*)al;
      *(uint4*)&Al[sr][sq * 8 + 8] = *(const uint4*)(al + 8);
      const unsigned short* bm = xhb + (size_t)(n0 + sr) * Cc + kc + sq * 8;
      *(uint4*)&Bh[sr][sq * 8] = *(const uint4*)bm;
      *(uint4*)&Bh[sr][sq * 8 + 8] = *(const uint4*)(bm + 8);
      const unsigned short* bl = xlb + (size_t)(n0 + sr) * Cc + kc + sq * 8;
      *(uint4*)&Bl[sr][sq * 8] = *(const uint4*)bl;
      *(uint4*)&Bl[sr][sq * 8 + 8] = *(const uint4*)(bl + 8);
    }
    __syncthreads();
    int ka = quad * 8;
    short8 a_h[4], a_l[4], b_h[4], b_l[4];
#pragma unroll
    for (int f = 0; f < 4; ++f) {
      a_h[f] = *(const short8*)&Ah[wm + f * 16 + l15][ka];
      a_l[f] = *(const short8*)&Al[wm + f * 16 + l15][ka];
      b_h[f] = *(const short8*)&Bh[wn + f * 16 + l15][ka];
      b_l[f] = *(const short8*)&Bl[wn + f * 16 + l15][ka];
    }
#pragma unroll
    for (int fm = 0; fm < 4; ++fm)
#pragma unroll
      for (int fn = 0; fn < 4; ++fn) {
        acc[fm][fn] = __builtin_amdgcn_mfma_f32_16x16x32_bf16(a_h[fm], b_h[fn], acc[fm][fn], 0, 0, 0);
        acc[fm][fn] = __builtin_amdgcn_mfma_f32_16x16x32_bf16(a_h[fm], b_l[fn], acc[fm][fn], 0, 0, 0);
        acc[fm][fn] = __builtin_amdgcn_mfma_f32_16x16x32_bf16(a_l[fm], b_h[fn], acc[fm][fn], 0, 0, 0);
      }
  }
#pragma unroll
  for (int fn = 0; fn < 4; ++fn) {
    int n = n0 + wn + fn * 16 + l15;
    float xv = xxb[n];
#pragma unroll
    for (int fm = 0; fm < 4; ++fm) {
      int m = m0 + wm + fm * 16 + quad * 4;
#pragma unroll
      for (int r = 0; r < 4; ++r)
        Sb[(size_t)(m + r) * Tt + n] = fmaf(2.f, acc[fm][fn][r], -xv);
    }
  }
}

// top-10 scan, 2 batches via z; wave per row, 8 rows per block
__global__ __launch_bounds__(512) void topk_scan(
    const float* __restrict__ S, int* __restrict__ idx10, int bbase) {
  int lb = blockIdx.z;
  int m = blockIdx.x * 8 + (threadIdx.x >> 6);
  int lane = threadIdx.x & 63;
  const float* row = S + ((size_t)lb * Tt + m) * Tt;
  float s[NTOP]; int idl[NTOP];
#pragma unroll
  for (int j = 0; j < NTOP; ++j) { s[j] = -INFINITY; idl[j] = 0x7fffffff; }
  for (int c0 = lane * 4; c0 < Tt; c0 += 256) {
    float4 v = *(const float4*)(row + c0);
    float cand[4] = {v.x, v.y, v.z, v.w};
#pragma unroll
    for (int e = 0; e < 4; ++e) {
      float sc = cand[e];
      if (sc > s[NTOP - 1]) {
        s[NTOP - 1] = sc; idl[NTOP - 1] = c0 + e;
#pragma unroll
        for (int j = NTOP - 1; j > 0; --j) {
          if (s[j] > s[j - 1]) {
            float ts = s[j]; s[j] = s[j - 1]; s[j - 1] = ts;
            int ti = idl[j]; idl[j] = idl[j - 1]; idl[j - 1] = ti;
          }
        }
      }
    }
  }
  int ptr = 0;
  for (int r = 0; r < NTOP; ++r) {
    float cs = (ptr < NTOP) ? s[ptr] : -INFINITY;
    int cid = (ptr < NTOP) ? idl[ptr] : 0x7fffffff;
    float bs = cs; int bi = cid;
#pragma unroll
    for (int off = 1; off < 64; off <<= 1) {
      float os = __shfl_xor(bs, off);
      int oi = __shfl_xor(bi, off);
      if (os > bs || (os == bs && oi < bi)) { bs = os; bi = oi; }
    }
    if (cid == bi) ptr++;
    if (lane == 0) idx10[((size_t)(bbase + lb) * Tt + m) * NTOP + r] = bi;
  }
}

// fp64 rescore of the NTOP shortlist, emit exact top-7
__global__ __launch_bounds__(64) void knn_rescore(
    const float* __restrict__ xT, const int* __restrict__ idx10,
    int* __restrict__ idxout) {
  int t = blockIdx.x;
  int b = blockIdx.y;
  int lane = threadIdx.x;
  const float* xTb = xT + (size_t)b * Tt * Cc;
  const float* xm = xTb + (size_t)t * Cc;
  double sc = -1e300;
  int cid = 0x7fffffff;
  if (lane < NTOP) {
    int j = idx10[((size_t)b * Tt + t) * NTOP + lane];
    const float* xn = xTb + (size_t)j * Cc;
    double dot = 0.0, nn = 0.0;
    for (int c = 0; c < Cc; c += 4) {
      float4 a = *(const float4*)(xm + c);
      float4 v = *(const float4*)(xn + c);
      dot += (double)a.x * v.x + (double)a.y * v.y + (double)a.z * v.z + (double)a.w * v.w;
      nn  += (double)v.x * v.x + (double)v.y * v.y + (double)v.z * v.z + (double)v.w * v.w;
    }
    sc = 2.0 * dot - nn;
    cid = j;
  }
  for (int r = 0; r < Kk; ++r) {
    double bs = sc; int bi = cid;
#pragma unroll
    for (int off = 1; off < 64; off <<= 1) {
      double os = __shfl_xor(bs, off);
      int oi = __shfl_xor(bi, off);
      if (os > bs || (os == bs && oi < bi)) { bs = os; bi = oi; }
    }
    if (cid == bi) { sc = -1e300; cid = 0x7fffffff; }
    if (lane == 0) idxout[((size_t)b * Tt + t) * Kk + r] = bi;
  }
}

// Fused graph tail + temporal conv. nbr consumed in [B,T,C] layout (nbrT):
// each (t,k) gather reads 8 channels as 2 contiguous float4s.
// NOTE (R1-R3 forensics): this structure is a verified local optimum.
//  - half-wave layout (ol=tid>>5, tl2=(tid&31)*2): lanes 32-63 broadcast-read
//    the same LDS addresses as lanes 0-31 (free). Wave-per-channel layouts
//    double LDS traffic and regress (R2: 125us vs 86us).
//  - packed floatx2 fma keeps codegen compact (52 VGPR). Scalar-fma rewrite
//    ballooned to 132 VGPR / 11% occupancy / 177us (R3).
//  - extra __launch_bounds__ min-wave args force spills (R1: 299MB scratch).
// FAST=0: exact erff (layer 1 -> x1 -> layer-2 KNN must be bit-stable).
// FAST=1: rational erf (layer 2 -> only final output).
template <int FAST>
__global__ __launch_bounds__(256) void graph_tail(
    const float* __restrict__ h, const float* __restrict__ ctr,
    const float* __restrict__ nbrT, const int* __restrict__ idx,
    const float* __restrict__ tw2, const float* __restrict__ tb2,
    const float* __restrict__ dw2, const float* __restrict__ db2,
    const float* __restrict__ xin, float* __restrict__ xout) {
  __shared__ __align__(16) float gt[CG][Kk][68];   // 14.9 KB
  __shared__ __align__(16) float ht[CG][68];       // 2.2 KB
  __shared__ __align__(16) float ct[CG][68];       // 2.2 KB
  __shared__ int jt[Kk * 68];                      // 1.9 KB, [k][tl]
  int t0 = blockIdx.x * 64;
  int g = blockIdx.y;
  int b = blockIdx.z;
  int tid = threadIdx.x;
  const float* hg   = h   + ((size_t)b * Cc + g * CG) * Tt;
  const float* ctrg = ctr + ((size_t)b * Cc + g * CG) * Tt;
  const float* nbT  = nbrT + (size_t)b * Tt * Cc + g * CG;

  {
    const int* ib = idx + ((size_t)b * Tt + t0 - 2) * Kk;
    for (int p = tid; p < Kk * 68; p += 256) {
      int k = p / 68, tl = p - k * 68;
      int tg = t0 - 2 + tl;
      jt[p] = (tg >= 0 && tg < Tt) ? ib[tl * Kk + k] : 0;
    }
    for (int e = tid; e < CG * 68; e += 256) {
      int ci = e / 68, tl = e - ci * 68;
      int tg = t0 - 2 + tl;
      int valid = (tg >= 0 && tg < Tt);
      ht[ci][tl] = valid ? hg[(size_t)ci * Tt + tg] : 0.f;
      ct[ci][tl] = valid ? ctrg[(size_t)ci * Tt + tg] : 0.f;
    }
  }
  __syncthreads();
  for (int p = tid; p < Kk * 68; p += 256) {
    int k = p / 68, tl = p - k * 68;
    int tg = t0 - 2 + tl;
    int valid = (tg >= 0 && tg < Tt);
    int j = jt[p];
    const float* np = nbT + (size_t)j * Cc;
    float4 n0 = *(const float4*)np;
    float4 n1 = *(const float4*)(np + 4);
    float ch[8] = {n0.x, n0.y, n0.z, n0.w, n1.x, n1.y, n1.z, n1.w};
#pragma unroll
    for (int ci = 0; ci < CG; ++ci) {
      float pre = ct[ci][tl] + ch[ci];
      float v = FAST ? gelu_fast(pre) : gelu_f(pre);
      gt[ci][k][tl] = valid ? v : 0.f;
    }
  }
  __syncthreads();

  int ol = tid >> 5, tl2 = (tid & 31) * 2;
  int o = g * CG + ol;

  const float* w2 = tw2 + (size_t)o * CG * 5;
  float bt = tb2[o];
  floatx2 acct = {bt, bt};
  for (int ci = 0; ci < CG; ++ci) {
    floatx2 p0 = *(const floatx2*)&ht[ci][tl2];
    floatx2 p1 = *(const floatx2*)&ht[ci][tl2 + 2];
    floatx2 p2 = *(const floatx2*)&ht[ci][tl2 + 4];
    float r6[6] = {p0.x, p0.y, p1.x, p1.y, p2.x, p2.y};
#pragma unroll
    for (int dt = 0; dt < 5; ++dt) {
      float wv = w2[ci * 5 + dt];
      floatx2 wv2 = {wv, wv};
      floatx2 rp = {r6[dt], r6[dt + 1]};
      acct = __builtin_elementwise_fma(wv2, rp, acct);
    }
  }

  const float* wp = dw2 + (size_t)o * CG * 25;
  float bv = db2[o];
  floatx2 acc[Kk];
#pragma unroll
  for (int k = 0; k < Kk; ++k) acc[k] = (floatx2){bv, bv};

  for (int ci = 0; ci < CG; ++ci) {
    float w[25];
#pragma unroll
    for (int i = 0; i < 25; ++i) w[i] = wp[ci * 25 + i];
#pragma unroll
    for (int kin = 0; kin < Kk; ++kin) {
      floatx2 p0 = *(const floatx2*)&gt[ci][kin][tl2];
      floatx2 p1 = *(const floatx2*)&gt[ci][kin][tl2 + 2];
      floatx2 p2 = *(const floatx2*)&gt[ci][kin][tl2 + 4];
      float r6[6] = {p0.x, p0.y, p1.x, p1.y, p2.x, p2.y};
      floatx2 rp[5];
#pragma unroll
      for (int dt = 0; dt < 5; ++dt) rp[dt] = (floatx2){r6[dt], r6[dt + 1]};
#pragma unroll
      for (int dk = 0; dk < 5; ++dk) {
        int k = kin + 2 - dk;
        if (k < 0 || k >= Kk) continue;
#pragma unroll
        for (int dt = 0; dt < 5; ++dt) {
          float wv = w[dt * 5 + dk];
          floatx2 wv2 = {wv, wv};
          acc[k] = __builtin_elementwise_fma(wv2, rp[dt], acc[k]);
        }
      }
    }
  }
  floatx2 m = acc[0];
#pragma unroll
  for (int k = 1; k < Kk; ++k) m = __builtin_elementwise_max(m, acc[k]);
  size_t off = ((size_t)b * Cc + o) * Tt + t0 + tl2;
  floatx2 xv = *(const floatx2*)&xin[off];
  floatx2 r;
  r.x = acct.x + m.x + xv.x;
  r.y = acct.y + m.y + xv.y;
  *(floatx2*)&xout[off] = r;
}

extern "C" void kernel_launch(void* const* d_in, const int* in_sizes, int n_in,
                              void* d_out, int out_size, void* d_ws, size_t ws_size,
                              hipStream_t stream) {
  const float* x0  = (const float*)d_in[0];
  const float* tw1 = (const float*)d_in[1];
  const float* tb1 = (const float*)d_in[2];
  const float* tw2 = (const float*)d_in[3];
  const float* tb2 = (const float*)d_in[4];
  const float* dw1 = (const float*)d_in[5];
  const float* db1 = (const float*)d_in[6];
  const float* dw2 = (const float*)d_in[7];
  const float* db2 = (const float*)d_in[8];
  float* out = (float*)d_out;

  float* ws = (float*)d_ws;
  const size_t NCT = (size_t)Bq * Cc * Tt;      // 2M elements
  float* x1   = ws;                             // layer-1 output   [B,C,T]
  float* hbuf = x1 + NCT;                       // h                [B,C,T]
  float* cbuf = hbuf + NCT;                     // ctr              [B,C,T]
  float* xT   = cbuf + NCT;                     // xT, then nbr     [B,T,C]
  unsigned short* xh = (unsigned short*)(xT + NCT);   // [B,T,C] bf16 hi
  unsigned short* xl = xh + NCT;                      // bf16 lo
  unsigned short* wh = xl + NCT;                      // weights hi [768][256]
  unsigned short* wl = wh + (size_t)NO * Cc;
  float* S    = (float*)(wl + (size_t)NO * Cc); // scores, 2 batches [2,T,T] 32MB
  float* xx   = S + 2 * (size_t)Tt * Tt;        // squared norms    [B,T]
  int* idxb   = (int*)(xx + (size_t)Bq * Tt);   // top-7            [B,T,K]
  int* idx10  = idxb + (size_t)Bq * Tt * Kk;    // top-10           [B,T,NTOP]
  float* nbrT = (float*)(idx10 + (size_t)Bq * Tt * NTOP);  // nbr^T [B,T,C] 8MB
  float* nbr  = xT;                             // nbr overwrites xT after rescore

  for (int i = 0; i < Ll; ++i) {
    const float* xin = (i == 0) ? x0 : x1;
    float* xout = (i == Ll - 1) ? out : x1;

    transpose_x<<<dim3(Tt/32, Cc/32, Bq), dim3(32, 8), 0, stream>>>(xin, xT, xh, xl);
    sqnorm_xt<<<dim3(Tt/8, Bq), 512, 0, stream>>>(xT, xx);
    for (int bp = 0; bp < Bq; bp += 2) {
      score_gemm<<<dim3(16, 16, 2), 256, 0, stream>>>(xh, xl, xx, S, bp);
      topk_scan<<<dim3(Tt/8, 1, 2), 512, 0, stream>>>(S, idx10, bp);
    }
    knn_rescore<<<dim3(Tt, Bq), 64, 0, stream>>>(xT, idx10, idxb);

    if (i == 0) {
      // Layer 1: exact fp32 pointwise convs (x1 feeds layer-2 KNN; R6/R7/R10 forensics)
      pw_conv8_all<<<dim3(Tt/1024, 96, Bq), 256, 0, stream>>>(
          xin, tw1 + (size_t)i * Cc * Cc, tb1 + (size_t)i * Cc,
          dw1 + (size_t)i * Cc * 2 * Cc, db1 + (size_t)i * Cc,
          hbuf, cbuf, nbr);
    } else {
      // Layer 2: split-bf16 MFMA GEMM — output feeds only the final result.
      wsplit<<<dim3(NO), 256, 0, stream>>>(
          tw1 + (size_t)i * Cc * Cc, dw1 + (size_t)i * Cc * 2 * Cc, wh, wl);
      pw_gemm<<<dim3(64, NO/128), 256, 0, stream>>>(
          wh, wl, xh, xl, tb1 + (size_t)i * Cc, db1 + (size_t)i * Cc,
          hbuf, cbuf, nbr);
    }
    // nbr -> nbrT [B,T,C] for transaction-efficient gathers in graph_tail
    transpose_f<<<dim3(Tt/32, Cc/32, Bq), dim3(32, 8), 0, stream>>>(nbr, nbrT);
    if (i == 0) {
      graph_tail<0><<<dim3(Tt/64, Cc/CG, Bq), 256, 0, stream>>>(
          hbuf, cbuf, nbrT, idxb, tw2 + (size_t)i * Cc * CG * 5, tb2 + (size_t)i * Cc,
          dw2 + (size_t)i * Cc * CG * 25, db2 + (size_t)i * Cc, xin, xout);
    } else {
      graph_tail<1><<<dim3(Tt/64, Cc/CG, Bq), 256, 0, stream>>>(
          hbuf, cbuf, nbrT, idxb, tw2 + (size_t)i * Cc * CG * 5, tb2 + (size_t)i * Cc,
          dw2 + (size_t)i * Cc * CG * 25, db2 + (size_t)i * Cc, xin, xout);
    }
  }
}

// Round 5
// 518.185 us; speedup vs baseline: 1.3590x; 1.0732x over previous
//
#include <hip/hip_runtime.h>
#include <math.h>

#define Bq 4
#define Cc 256
#define Tt 2048
#define Kk 7
#define NTOP 10
#define CG 8
#define Ll 2
#define NO 768   // fused pointwise outputs: 256 h | 256 ctr | 256 nbr

typedef __attribute__((ext_vector_type(8))) short short8;
typedef __attribute__((ext_vector_type(4))) float floatx4;
typedef __attribute__((ext_vector_type(2))) float floatx2;

__device__ __forceinline__ float gelu_f(float v) {
  return 0.5f * v * (1.0f + erff(v * 0.70710678118654752440f));
}

// A&S 7.1.26 rational erf (~1e-6 eff err in fp32). SAFE ONLY on paths that do
// not feed a later top-k: R10 proved a ~1e-6 x1 perturbation flips layer-2 KNN.
__device__ __forceinline__ float erf_fast(float x) {
  float ax = fabsf(x);
  float t = __builtin_amdgcn_rcpf(fmaf(0.3275911f, ax, 1.0f));
  float y = t * (0.254829592f + t * (-0.284496736f + t * (1.421413741f +
            t * (-1.453152027f + t * 1.061405429f))));
  float r = 1.0f - y * __expf(-ax * ax);
  return copysignf(r, x);
}
__device__ __forceinline__ float gelu_fast(float v) {
  return 0.5f * v * (1.0f + erf_fast(v * 0.70710678118654752440f));
}

// xT[b][t][c] = x[b][c][t]; also emits bf16 hi/lo split
__global__ void transpose_x(const float* __restrict__ x, float* __restrict__ xT,
                            unsigned short* __restrict__ xh,
                            unsigned short* __restrict__ xl) {
  __shared__ float tile[32][33];
  int b = blockIdx.z;
  int t0 = blockIdx.x * 32, c0 = blockIdx.y * 32;
  int tx = threadIdx.x, ty = threadIdx.y;
  const float* xb = x + (size_t)b * Cc * Tt;
  for (int r = ty; r < 32; r += 8)
    tile[r][tx] = xb[(size_t)(c0 + r) * Tt + t0 + tx];
  __syncthreads();
  size_t base = (size_t)b * Tt * Cc;
  for (int r = ty; r < 32; r += 8) {
    float v = tile[tx][r];
    size_t o = base + (size_t)(t0 + r) * Cc + c0 + tx;
    xT[o] = v;
    unsigned int u = __float_as_uint(v);
    unsigned short h = (unsigned short)((u + 0x7fffu + ((u >> 16) & 1u)) >> 16);
    float f = v - __uint_as_float((unsigned int)h << 16);
    unsigned int ul = __float_as_uint(f);
    xh[o] = h;
    xl[o] = (unsigned short)((ul + 0x7fffu + ((ul >> 16) & 1u)) >> 16);
  }
}

// plain fp32 transpose: dst[b][t][c] = src[b][c][t]  (for nbr -> nbrT)
__global__ void transpose_f(const float* __restrict__ src, float* __restrict__ dst) {
  __shared__ float tile[32][33];
  int b = blockIdx.z;
  int t0 = blockIdx.x * 32, c0 = blockIdx.y * 32;
  int tx = threadIdx.x, ty = threadIdx.y;
  const float* sb = src + (size_t)b * Cc * Tt;
  for (int r = ty; r < 32; r += 8)
    tile[r][tx] = sb[(size_t)(c0 + r) * Tt + t0 + tx];
  __syncthreads();
  float* db = dst + (size_t)b * Tt * Cc;
  for (int r = ty; r < 32; r += 8)
    db[(size_t)(t0 + r) * Cc + c0 + tx] = tile[tx][r];
}

// squared norms from xT; wave per row t, 8 rows per block
__global__ __launch_bounds__(512) void sqnorm_xt(
    const float* __restrict__ xT, float* __restrict__ xx) {
  int b = blockIdx.y;
  int t = blockIdx.x * 8 + (threadIdx.x >> 6);
  int lane = threadIdx.x & 63;
  const float* row = xT + ((size_t)b * Tt + t) * Cc;
  float4 v = *(const float4*)(row + lane * 4);
  float acc = v.x * v.x + v.y * v.y + v.z * v.z + v.w * v.w;
#pragma unroll
  for (int off = 1; off < 64; off <<= 1) acc += __shfl_xor(acc, off);
  if (lane == 0) xx[(size_t)b * Tt + t] = acc;
}

// fp32 pointwise convs, all 3 ranges in one launch (layer-1 exact path).
// Thread = 8 outputs x 4 tokens, float4 x-loads (32 FMA per load vs 8 before).
// Per-(o,t) fmaf chain remains bias -> ascending c  ==> bit-identical to R12.
__global__ __launch_bounds__(256) void pw_conv8_all(
    const float* __restrict__ x, const float* __restrict__ tw1,
    const float* __restrict__ tb1, const float* __restrict__ dw1,
    const float* __restrict__ db1, float* __restrict__ hb,
    float* __restrict__ cb, float* __restrict__ nb) {
  int tid = threadIdx.x;
  int wv = tid >> 6, lane = tid & 63;
  int t = blockIdx.x * 1024 + wv * 256 + lane * 4;   // 4 consecutive tokens
  int oy = blockIdx.y;
  int b = blockIdx.z;
  int range = oy >> 5;            // 0: h  1: ctr  2: nbr
  int o0 = (oy & 31) * 8;
  const float* W; int wstride, woff; const float* bias; float* dst; int dg;
  if (range == 0)      { W = tw1; wstride = Cc;     woff = 0;  bias = tb1;     dst = hb; dg = 1; }
  else if (range == 1) { W = dw1; wstride = 2 * Cc; woff = Cc; bias = db1;     dst = cb; dg = 0; }
  else                 { W = dw1; wstride = 2 * Cc; woff = 0;  bias = nullptr; dst = nb; dg = 0; }
  const float* xp = x + (size_t)b * Cc * Tt + t;
  const float* wp = W + (size_t)o0 * wstride + woff;
  float acc[8][4];
#pragma unroll
  for (int j = 0; j < 8; ++j) {
    float bv = bias ? bias[o0 + j] : 0.f;
#pragma unroll
    for (int e = 0; e < 4; ++e) acc[j][e] = bv;
  }
  for (int c = 0; c < Cc; c += 4) {
    float4 xv0 = *(const float4*)(xp + (size_t)c * Tt);
    float4 xv1 = *(const float4*)(xp + (size_t)(c + 1) * Tt);
    float4 xv2 = *(const float4*)(xp + (size_t)(c + 2) * Tt);
    float4 xv3 = *(const float4*)(xp + (size_t)(c + 3) * Tt);
    float x0[4] = {xv0.x, xv0.y, xv0.z, xv0.w};
    float x1[4] = {xv1.x, xv1.y, xv1.z, xv1.w};
    float x2[4] = {xv2.x, xv2.y, xv2.z, xv2.w};
    float x3[4] = {xv3.x, xv3.y, xv3.z, xv3.w};
#pragma unroll
    for (int j = 0; j < 8; ++j) {
      const float* wr = wp + (size_t)j * wstride + c;   // wave-uniform -> s_load
      float w0 = wr[0], w1 = wr[1], w2 = wr[2], w3 = wr[3];
#pragma unroll
      for (int e = 0; e < 4; ++e) {
        float a = acc[j][e];
        a = fmaf(w0, x0[e], a);
        a = fmaf(w1, x1[e], a);
        a = fmaf(w2, x2[e], a);
        a = fmaf(w3, x3[e], a);
        acc[j][e] = a;
      }
    }
  }
#pragma unroll
  for (int j = 0; j < 8; ++j) {
    float4 r;
    float* rp = (float*)&r;
#pragma unroll
    for (int e = 0; e < 4; ++e) {
      float v = acc[j][e];
      if (dg) v = gelu_f(v);
      rp[e] = v;
    }
    *(float4*)&dst[((size_t)b * Cc + o0 + j) * Tt + t] = r;
  }
}

// concat weights [768][256] -> bf16 hi/lo (layer-2 only)
__global__ __launch_bounds__(256) void wsplit(
    const float* __restrict__ tw1, const float* __restrict__ dw1,
    unsigned short* __restrict__ wh, unsigned short* __restrict__ wl) {
  int o = blockIdx.x;
  int c = threadIdx.x;
  float v;
  if (o < 256) v = tw1[(size_t)o * Cc + c];
  else if (o < 512) v = dw1[(size_t)(o - 256) * (2 * Cc) + Cc + c];
  else v = dw1[(size_t)(o - 512) * (2 * Cc) + c];
  unsigned int u = __float_as_uint(v);
  unsigned short h = (unsigned short)((u + 0x7fffu + ((u >> 16) & 1u)) >> 16);
  float f = v - __uint_as_float((unsigned int)h << 16);
  unsigned int ul = __float_as_uint(f);
  wh[(size_t)o * Cc + c] = h;
  wl[(size_t)o * Cc + c] = (unsigned short)((ul + 0x7fffu + ((ul >> 16) & 1u)) >> 16);
}

// fused pointwise GEMM (layer-2 only)
__global__ __launch_bounds__(256) void pw_gemm(
    const unsigned short* __restrict__ wh, const unsigned short* __restrict__ wl,
    const unsigned short* __restrict__ xh, const unsigned short* __restrict__ xl,
    const float* __restrict__ tb1, const float* __restrict__ db1,
    float* __restrict__ hb, float* __restrict__ cb, float* __restrict__ nb) {
  __shared__ __align__(16) unsigned short Ah[128][40], Al[128][40];
  __shared__ __align__(16) unsigned short Bh[128][40], Bl[128][40];
  int mt = blockIdx.x;
  int b = mt >> 4;
  int t0 = (mt & 15) * 128;
  int o0 = blockIdx.y * 128;
  int tid = threadIdx.x;
  int w = tid >> 6, lane = tid & 63, quad = lane >> 4, l15 = lane & 15;
  int wm = (w >> 1) * 64, wn = (w & 1) * 64;
  floatx4 acc[4][4];
#pragma unroll
  for (int i = 0; i < 4; ++i)
#pragma unroll
    for (int j = 0; j < 4; ++j) acc[i][j] = (floatx4){0.f, 0.f, 0.f, 0.f};

  const unsigned short* xhb = xh + ((size_t)b * Tt + t0) * Cc;
  const unsigned short* xlb = xl + ((size_t)b * Tt + t0) * Cc;
  int sr = tid >> 1;
  int sq = (tid & 1) * 2;
  for (int kc = 0; kc < Cc; kc += 32) {
    __syncthreads();
    {
      const unsigned short* am = wh + (size_t)(o0 + sr) * Cc + kc + sq * 8;
      *(uint4*)&Ah[sr][sq * 8] = *(const uint4*)am;
      *(uint4*)&Ah[sr][sq * 8 + 8] = *(const uint4*)(am + 8);
      const unsigned short* al = wl + (size_t)(o0 + sr) * Cc + kc + sq * 8;
      *(uint4*)&Al[sr][sq * 8] = *(const uint4*)al;
      *(uint4*)&Al[sr][sq * 8 + 8] = *(const uint4*)(al + 8);
      const unsigned short* bm = xhb + (size_t)sr * Cc + kc + sq * 8;
      *(uint4*)&Bh[sr][sq * 8] = *(const uint4*)bm;
      *(uint4*)&Bh[sr][sq * 8 + 8] = *(const uint4*)(bm + 8);
      const unsigned short* bl = xlb + (size_t)sr * Cc + kc + sq * 8;
      *(uint4*)&Bl[sr][sq * 8] = *(const uint4*)bl;
      *(uint4*)&Bl[sr][sq * 8 + 8] = *(const uint4*)(bl + 8);
    }
    __syncthreads();
    int ka = quad * 8;
    short8 a_h[4], a_l[4], b_h[4], b_l[4];
#pragma unroll
    for (int f = 0; f < 4; ++f) {
      a_h[f] = *(const short8*)&Ah[wm + f * 16 + l15][ka];
      a_l[f] = *(const short8*)&Al[wm + f * 16 + l15][ka];
      b_h[f] = *(const short8*)&Bh[wn + f * 16 + l15][ka];
      b_l[f] = *(const short8*)&Bl[wn + f * 16 + l15][ka];
    }
#pragma unroll
    for (int fm = 0; fm < 4; ++fm)
#pragma unroll
      for (int fn = 0; fn < 4; ++fn) {
        acc[fm][fn] = __builtin_amdgcn_mfma_f32_16x16x32_bf16(a_h[fm], b_h[fn], acc[fm][fn], 0, 0, 0);
        acc[fm][fn] = __builtin_amdgcn_mfma_f32_16x16x32_bf16(a_h[fm], b_l[fn], acc[fm][fn], 0, 0, 0);
        acc[fm][fn] = __builtin_amdgcn_mfma_f32_16x16x32_bf16(a_l[fm], b_h[fn], acc[fm][fn], 0, 0, 0);
      }
  }
  int range = o0 >> 8;                 // 0: h(gelu,tb1)  1: ctr(db1)  2: nbr
  float* dst = (range == 0) ? hb : (range == 1) ? cb : nb;
  const float* bias = (range == 0) ? tb1 : (range == 1) ? db1 : nullptr;
  int ol0 = o0 & 255;
#pragma unroll
  for (int fm = 0; fm < 4; ++fm) {
    int o = ol0 + wm + fm * 16 + quad * 4;
#pragma unroll
    for (int r = 0; r < 4; ++r) {
      float bv = bias ? bias[o + r] : 0.f;
      size_t rowoff = ((size_t)b * Cc + o + r) * Tt + t0;
#pragma unroll
      for (int fn = 0; fn < 4; ++fn) {
        int t = wn + fn * 16 + l15;
        float v = acc[fm][fn][r] + bv;
        if (range == 0) v = gelu_f(v);
        dst[rowoff + t] = v;
      }
    }
  }
}

// score GEMM, 2 batches per dispatch via z
__global__ __launch_bounds__(256) void score_gemm(
    const unsigned short* __restrict__ xh, const unsigned short* __restrict__ xl,
    const float* __restrict__ xx, float* __restrict__ S, int bbase) {
  __shared__ __align__(16) unsigned short Ah[128][40], Al[128][40];
  __shared__ __align__(16) unsigned short Bh[128][40], Bl[128][40];
  int lb = blockIdx.z;
  int b = bbase + lb;
  int m0 = blockIdx.y * 128, n0 = blockIdx.x * 128;
  int tid = threadIdx.x;
  int w = tid >> 6, lane = tid & 63, quad = lane >> 4, l15 = lane & 15;
  int wm = (w >> 1) * 64, wn = (w & 1) * 64;
  const unsigned short* xhb = xh + (size_t)b * Tt * Cc;
  const unsigned short* xlb = xl + (size_t)b * Tt * Cc;
  const float* xxb = xx + (size_t)b * Tt;
  float* Sb = S + (size_t)lb * Tt * Tt;
  floatx4 acc[4][4];
#pragma unroll
  for (int i = 0; i < 4; ++i)
#pragma unroll
    for (int j = 0; j < 4; ++j) acc[i][j] = (floatx4){0.f, 0.f, 0.f, 0.f};

  int sr = tid >> 1;
  int sq = (tid & 1) * 2;
  for (int kc = 0; kc < Cc; kc += 32) {
    __syncthreads();
    {
      const unsigned short* am = xhb + (size_t)(m0 + sr) * Cc + kc + sq * 8;
      *(uint4*)&Ah[sr][sq * 8] = *(const uint4*)am;
      *(uint4*)&Ah[sr][sq * 8 + 8] = *(const uint4*)(am + 8);
      const unsigned short* al = xlb + (size_t)(m0 + sr) * Cc + kc + sq * 8;
      *(uint4*)&Al[sr][sq * 8] = *(const uint4*)al;
      *(uint4*)&Al[sr][sq * 8 + 8] = *(const uint4*)(al + 8);
      const unsigned short* bm = xhb + (size_t)(n0 + sr) * Cc + kc + sq * 8;
      *(uint4*)&Bh[sr][sq * 8] = *(const uint4*)bm;
      *(uint4*)&Bh[sr][sq * 8 + 8] = *(const uint4*)(bm + 8);
      const unsigned short* bl = xlb + (size_t)(n0 + sr) * Cc + kc + sq * 8;
      *(uint4*)&Bl[sr][sq * 8] = *(const uint4*)bl;
      *(uint4*)&Bl[sr][sq * 8 + 8] = *(const uint4*)(bl + 8);
    }
    __syncthreads();
    int ka = quad * 8;
    short8 a_h[4], a_l[4], b_h[4], b_l[4];
#pragma unroll
    for (int f = 0; f < 4; ++f) {
      a_h[f] = *(const short8*)&Ah[wm + f * 16 + l15][ka];
      a_l[f] = *(const short8*)&Al[wm + f * 16 + l15][ka];
      b_h[f] = *(const short8*)&Bh[wn + f * 16 + l15][ka];
      b_l[f] = *(const short8*)&Bl[wn + f * 16 + l15][ka];
    }
#pragma unroll
    for (int fm = 0; fm < 4; ++fm)
#pragma unroll
      for (int fn = 0; fn < 4; ++fn) {
        acc[fm][fn] = __builtin_amdgcn_mfma_f32_16x16x32_bf16(a_h[fm], b_h[fn], acc[fm][fn], 0, 0, 0);
        acc[fm][fn] = __builtin_amdgcn_mfma_f32_16x16x32_bf16(a_h[fm], b_l[fn], acc[fm][fn], 0, 0, 0);
        acc[fm][fn] = __builtin_amdgcn_mfma_f32_16x16x32_bf16(a_l[fm], b_h[fn], acc[fm][fn], 0, 0, 0);
      }
  }
#pragma unroll
  for (int fn = 0; fn < 4; ++fn) {
    int n = n0 + wn + fn * 16 + l15;
    float xv = xxb[n];
#pragma unroll
    for (int fm = 0; fm < 4; ++fm) {
      int m = m0 + wm + fm * 16 + quad * 4;
#pragma unroll
      for (int r = 0; r < 4; ++r)
        Sb[(size_t)(m + r) * Tt + n] = fmaf(2.f, acc[fm][fn][r], -xv);
    }
  }
}

// top-10 scan, 2 batches via z; wave per row, 8 rows per block
__global__ __launch_bounds__(512) void topk_scan(
    const float* __restrict__ S, int* __restrict__ idx10, int bbase) {
  int lb = blockIdx.z;
  int m = blockIdx.x * 8 + (threadIdx.x >> 6);
  int lane = threadIdx.x & 63;
  const float* row = S + ((size_t)lb * Tt + m) * Tt;
  float s[NTOP]; int idl[NTOP];
#pragma unroll
  for (int j = 0; j < NTOP; ++j) { s[j] = -INFINITY; idl[j] = 0x7fffffff; }
  for (int c0 = lane * 4; c0 < Tt; c0 += 256) {
    float4 v = *(const float4*)(row + c0);
    float cand[4] = {v.x, v.y, v.z, v.w};
#pragma unroll
    for (int e = 0; e < 4; ++e) {
      float sc = cand[e];
      if (sc > s[NTOP - 1]) {
        s[NTOP - 1] = sc; idl[NTOP - 1] = c0 + e;
#pragma unroll
        for (int j = NTOP - 1; j > 0; --j) {
          if (s[j] > s[j - 1]) {
            float ts = s[j]; s[j] = s[j - 1]; s[j - 1] = ts;
            int ti = idl[j]; idl[j] = idl[j - 1]; idl[j - 1] = ti;
          }
        }
      }
    }
  }
  int ptr = 0;
  for (int r = 0; r < NTOP; ++r) {
    float cs = (ptr < NTOP) ? s[ptr] : -INFINITY;
    int cid = (ptr < NTOP) ? idl[ptr] : 0x7fffffff;
    float bs = cs; int bi = cid;
#pragma unroll
    for (int off = 1; off < 64; off <<= 1) {
      float os = __shfl_xor(bs, off);
      int oi = __shfl_xor(bi, off);
      if (os > bs || (os == bs && oi < bi)) { bs = os; bi = oi; }
    }
    if (cid == bi) ptr++;
    if (lane == 0) idx10[((size_t)(bbase + lb) * Tt + m) * NTOP + r] = bi;
  }
}

// fp64 rescore of the NTOP shortlist, emit exact top-7.
// v2 (R4->R5): wave-parallel. Old: 10/64 lanes active, 64-iter serial fp64
// chain per lane (~84% idle). New: lane = (cand = lane&15, part = lane>>4);
// 40 active lanes, each part covers 64 channels; partial fp64 sums reduced
// via shfl_xor(16/32) (xor preserves cand group). 4 t's per 256-thr block.
// Numerics: only fp64 summation GROUPING changes (chunked tree vs serial);
// fp64 ranking of distinct candidates is unaffected at 2^-50 level; exact
// duplicates still yield bit-identical scores (same per-cand code) -> idx
// tie-break unchanged -> emitted top-7 identical.
__global__ __launch_bounds__(256) void knn_rescore(
    const float* __restrict__ xT, const int* __restrict__ idx10,
    int* __restrict__ idxout) {
  int t = blockIdx.x * 4 + (threadIdx.x >> 6);
  int b = blockIdx.y;
  int lane = threadIdx.x & 63;
  int cand = lane & 15;
  int part = lane >> 4;                 // 0..3, 64 channels each
  const float* xTb = xT + (size_t)b * Tt * Cc;
  const float* xm = xTb + (size_t)t * Cc;
  double dot = 0.0, nn = 0.0;
  int j = 0x7fffffff;
  bool act = (cand < NTOP);
  if (act) {
    j = idx10[((size_t)b * Tt + t) * NTOP + cand];
    const float* xn = xTb + (size_t)j * Cc;
    int c0 = part * 64;
    for (int c = c0; c < c0 + 64; c += 4) {
      float4 a = *(const float4*)(xm + c);
      float4 v = *(const float4*)(xn + c);
      dot += (double)a.x * v.x + (double)a.y * v.y + (double)a.z * v.z + (double)a.w * v.w;
      nn  += (double)v.x * v.x + (double)v.y * v.y + (double)v.z * v.z + (double)v.w * v.w;
    }
  }
  // combine the 4 parts of each cand (lanes {c, c+16, c+32, c+48})
  dot += __shfl_xor(dot, 16);
  nn  += __shfl_xor(nn, 16);
  dot += __shfl_xor(dot, 32);
  nn  += __shfl_xor(nn, 32);
  double sc = act ? (2.0 * dot - nn) : -1e300;
  int cid = act ? j : 0x7fffffff;
  for (int r = 0; r < Kk; ++r) {
    double bs = sc; int bi = cid;
#pragma unroll
    for (int off = 1; off < 64; off <<= 1) {
      double os = __shfl_xor(bs, off);
      int oi = __shfl_xor(bi, off);
      if (os > bs || (os == bs && oi < bi)) { bs = os; bi = oi; }
    }
    if (cid == bi) { sc = -1e300; cid = 0x7fffffff; }   // clears all 4 copies
    if (lane == 0) idxout[((size_t)b * Tt + t) * Kk + r] = bi;
  }
}

// Fused graph tail + temporal conv. nbr consumed in [B,T,C] layout (nbrT):
// each (t,k) gather reads 8 channels as 2 contiguous float4s.
// NOTE (R1-R3 forensics): this structure is a verified local optimum.
//  - half-wave layout (ol=tid>>5, tl2=(tid&31)*2): lanes 32-63 broadcast-read
//    the same LDS addresses as lanes 0-31 (free). Wave-per-channel layouts
//    double LDS traffic and regress (R2: 125us vs 86us).
//  - packed floatx2 fma keeps codegen compact (52 VGPR). Scalar-fma rewrite
//    ballooned to 132 VGPR / 11% occupancy / 177us (R3).
//  - extra __launch_bounds__ min-wave args force spills (R1: 299MB scratch).
// FAST=0: exact erff (layer 1 -> x1 -> layer-2 KNN must be bit-stable).
// FAST=1: rational erf (layer 2 -> only final output).
template <int FAST>
__global__ __launch_bounds__(256) void graph_tail(
    const float* __restrict__ h, const float* __restrict__ ctr,
    const float* __restrict__ nbrT, const int* __restrict__ idx,
    const float* __restrict__ tw2, const float* __restrict__ tb2,
    const float* __restrict__ dw2, const float* __restrict__ db2,
    const float* __restrict__ xin, float* __restrict__ xout) {
  __shared__ __align__(16) float gt[CG][Kk][68];   // 14.9 KB
  __shared__ __align__(16) float ht[CG][68];       // 2.2 KB
  __shared__ __align__(16) float ct[CG][68];       // 2.2 KB
  __shared__ int jt[Kk * 68];                      // 1.9 KB, [k][tl]
  int t0 = blockIdx.x * 64;
  int g = blockIdx.y;
  int b = blockIdx.z;
  int tid = threadIdx.x;
  const float* hg   = h   + ((size_t)b * Cc + g * CG) * Tt;
  const float* ctrg = ctr + ((size_t)b * Cc + g * CG) * Tt;
  const float* nbT  = nbrT + (size_t)b * Tt * Cc + g * CG;

  {
    const int* ib = idx + ((size_t)b * Tt + t0 - 2) * Kk;
    for (int p = tid; p < Kk * 68; p += 256) {
      int k = p / 68, tl = p - k * 68;
      int tg = t0 - 2 + tl;
      jt[p] = (tg >= 0 && tg < Tt) ? ib[tl * Kk + k] : 0;
    }
    for (int e = tid; e < CG * 68; e += 256) {
      int ci = e / 68, tl = e - ci * 68;
      int tg = t0 - 2 + tl;
      int valid = (tg >= 0 && tg < Tt);
      ht[ci][tl] = valid ? hg[(size_t)ci * Tt + tg] : 0.f;
      ct[ci][tl] = valid ? ctrg[(size_t)ci * Tt + tg] : 0.f;
    }
  }
  __syncthreads();
  for (int p = tid; p < Kk * 68; p += 256) {
    int k = p / 68, tl = p - k * 68;
    int tg = t0 - 2 + tl;
    int valid = (tg >= 0 && tg < Tt);
    int j = jt[p];
    const float* np = nbT + (size_t)j * Cc;
    float4 n0 = *(const float4*)np;
    float4 n1 = *(const float4*)(np + 4);
    float ch[8] = {n0.x, n0.y, n0.z, n0.w, n1.x, n1.y, n1.z, n1.w};
#pragma unroll
    for (int ci = 0; ci < CG; ++ci) {
      float pre = ct[ci][tl] + ch[ci];
      float v = FAST ? gelu_fast(pre) : gelu_f(pre);
      gt[ci][k][tl] = valid ? v : 0.f;
    }
  }
  __syncthreads();

  int ol = tid >> 5, tl2 = (tid & 31) * 2;
  int o = g * CG + ol;

  const float* w2 = tw2 + (size_t)o * CG * 5;
  float bt = tb2[o];
  floatx2 acct = {bt, bt};
  for (int ci = 0; ci < CG; ++ci) {
    floatx2 p0 = *(const floatx2*)&ht[ci][tl2];
    floatx2 p1 = *(const floatx2*)&ht[ci][tl2 + 2];
    floatx2 p2 = *(const floatx2*)&ht[ci][tl2 + 4];
    float r6[6] = {p0.x, p0.y, p1.x, p1.y, p2.x, p2.y};
#pragma unroll
    for (int dt = 0; dt < 5; ++dt) {
      float wv = w2[ci * 5 + dt];
      floatx2 wv2 = {wv, wv};
      floatx2 rp = {r6[dt], r6[dt + 1]};
      acct = __builtin_elementwise_fma(wv2, rp, acct);
    }
  }

  const float* wp = dw2 + (size_t)o * CG * 25;
  float bv = db2[o];
  floatx2 acc[Kk];
#pragma unroll
  for (int k = 0; k < Kk; ++k) acc[k] = (floatx2){bv, bv};

  for (int ci = 0; ci < CG; ++ci) {
    float w[25];
#pragma unroll
    for (int i = 0; i < 25; ++i) w[i] = wp[ci * 25 + i];
#pragma unroll
    for (int kin = 0; kin < Kk; ++kin) {
      floatx2 p0 = *(const floatx2*)&gt[ci][kin][tl2];
      floatx2 p1 = *(const floatx2*)&gt[ci][kin][tl2 + 2];
      floatx2 p2 = *(const floatx2*)&gt[ci][kin][tl2 + 4];
      float r6[6] = {p0.x, p0.y, p1.x, p1.y, p2.x, p2.y};
      floatx2 rp[5];
#pragma unroll
      for (int dt = 0; dt < 5; ++dt) rp[dt] = (floatx2){r6[dt], r6[dt + 1]};
#pragma unroll
      for (int dk = 0; dk < 5; ++dk) {
        int k = kin + 2 - dk;
        if (k < 0 || k >= Kk) continue;
#pragma unroll
        for (int dt = 0; dt < 5; ++dt) {
          float wv = w[dt * 5 + dk];
          floatx2 wv2 = {wv, wv};
          acc[k] = __builtin_elementwise_fma(wv2, rp[dt], acc[k]);
        }
      }
    }
  }
  floatx2 m = acc[0];
#pragma unroll
  for (int k = 1; k < Kk; ++k) m = __builtin_elementwise_max(m, acc[k]);
  size_t off = ((size_t)b * Cc + o) * Tt + t0 + tl2;
  floatx2 xv = *(const floatx2*)&xin[off];
  floatx2 r;
  r.x = acct.x + m.x + xv.x;
  r.y = acct.y + m.y + xv.y;
  *(floatx2*)&xout[off] = r;
}

extern "C" void kernel_launch(void* const* d_in, const int* in_sizes, int n_in,
                              void* d_out, int out_size, void* d_ws, size_t ws_size,
                              hipStream_t stream) {
  const float* x0  = (const float*)d_in[0];
  const float* tw1 = (const float*)d_in[1];
  const float* tb1 = (const float*)d_in[2];
  const float* tw2 = (const float*)d_in[3];
  const float* tb2 = (const float*)d_in[4];
  const float* dw1 = (const float*)d_in[5];
  const float* db1 = (const float*)d_in[6];
  const float* dw2 = (const float*)d_in[7];
  const float* db2 = (const float*)d_in[8];
  float* out = (float*)d_out;

  float* ws = (float*)d_ws;
  const size_t NCT = (size_t)Bq * Cc * Tt;      // 2M elements
  float* x1   = ws;                             // layer-1 output   [B,C,T]
  float* hbuf = x1 + NCT;                       // h                [B,C,T]
  float* cbuf = hbuf + NCT;                     // ctr              [B,C,T]
  float* xT   = cbuf + NCT;                     // xT, then nbr     [B,T,C]
  unsigned short* xh = (unsigned short*)(xT + NCT);   // [B,T,C] bf16 hi
  unsigned short* xl = xh + NCT;                      // bf16 lo
  unsigned short* wh = xl + NCT;                      // weights hi [768][256]
  unsigned short* wl = wh + (size_t)NO * Cc;
  float* S    = (float*)(wl + (size_t)NO * Cc); // scores, 2 batches [2,T,T] 32MB
  float* xx   = S + 2 * (size_t)Tt * Tt;        // squared norms    [B,T]
  int* idxb   = (int*)(xx + (size_t)Bq * Tt);   // top-7            [B,T,K]
  int* idx10  = idxb + (size_t)Bq * Tt * Kk;    // top-10           [B,T,NTOP]
  float* nbrT = (float*)(idx10 + (size_t)Bq * Tt * NTOP);  // nbr^T [B,T,C] 8MB
  float* nbr  = xT;                             // nbr overwrites xT after rescore

  for (int i = 0; i < Ll; ++i) {
    const float* xin = (i == 0) ? x0 : x1;
    float* xout = (i == Ll - 1) ? out : x1;

    transpose_x<<<dim3(Tt/32, Cc/32, Bq), dim3(32, 8), 0, stream>>>(xin, xT, xh, xl);
    sqnorm_xt<<<dim3(Tt/8, Bq), 512, 0, stream>>>(xT, xx);
    for (int bp = 0; bp < Bq; bp += 2) {
      score_gemm<<<dim3(16, 16, 2), 256, 0, stream>>>(xh, xl, xx, S, bp);
      topk_scan<<<dim3(Tt/8, 1, 2), 512, 0, stream>>>(S, idx10, bp);
    }
    knn_rescore<<<dim3(Tt/4, Bq), 256, 0, stream>>>(xT, idx10, idxb);

    if (i == 0) {
      // Layer 1: exact fp32 pointwise convs (x1 feeds layer-2 KNN; R6/R7/R10 forensics)
      pw_conv8_all<<<dim3(Tt/1024, 96, Bq), 256, 0, stream>>>(
          xin, tw1 + (size_t)i * Cc * Cc, tb1 + (size_t)i * Cc,
          dw1 + (size_t)i * Cc * 2 * Cc, db1 + (size_t)i * Cc,
          hbuf, cbuf, nbr);
    } else {
      // Layer 2: split-bf16 MFMA GEMM — output feeds only the final result.
      wsplit<<<dim3(NO), 256, 0, stream>>>(
          tw1 + (size_t)i * Cc * Cc, dw1 + (size_t)i * Cc * 2 * Cc, wh, wl);
      pw_gemm<<<dim3(64, NO/128), 256, 0, stream>>>(
          wh, wl, xh, xl, tb1 + (size_t)i * Cc, db1 + (size_t)i * Cc,
          hbuf, cbuf, nbr);
    }
    // nbr -> nbrT [B,T,C] for transaction-efficient gathers in graph_tail
    transpose_f<<<dim3(Tt/32, Cc/32, Bq), dim3(32, 8), 0, stream>>>(nbr, nbrT);
    if (i == 0) {
      graph_tail<0><<<dim3(Tt/64, Cc/CG, Bq), 256, 0, stream>>>(
          hbuf, cbuf, nbrT, idxb, tw2 + (size_t)i * Cc * CG * 5, tb2 + (size_t)i * Cc,
          dw2 + (size_t)i * Cc * CG * 25, db2 + (size_t)i * Cc, xin, xout);
    } else {
      graph_tail<1><<<dim3(Tt/64, Cc/CG, Bq), 256, 0, stream>>>(
          hbuf, cbuf, nbrT, idxb, tw2 + (size_t)i * Cc * CG * 5, tb2 + (size_t)i * Cc,
          dw2 + (size_t)i * Cc * CG * 25, db2 + (size_t)i * Cc, xin, xout);
    }
  }
}